// Round 14
// baseline (1608.681 us; speedup 1.0000x reference)
//
#include <hip/hip_runtime.h>

#define K_IN 256
#define N_OUT 64
#define RPB 128          // rows per bucket
#define MAX_NB 1024      // max buckets (supports n <= 131072)
#define MS_CHUNK 4096    // edges per multisplit block

typedef float __attribute__((ext_vector_type(4))) f32x4;
typedef int   __attribute__((ext_vector_type(2))) i32x2;

// ---------------- GEMM: XW = X @ W  (fp32 vector, 64x64 tile, 4x4/thread) ---
__global__ __launch_bounds__(256) void gemm_xw(const float* __restrict__ X,
                                               const float* __restrict__ W,
                                               float* __restrict__ XW, int n) {
  __shared__ float Xs[64][68];
  __shared__ float Ws[64][68];
  const int tid = threadIdx.x;
  const int row0 = blockIdx.x * 64;
  const int tx = tid & 15;
  const int ty = tid >> 4;
  float acc[4][4] = {};
  for (int kc = 0; kc < K_IN; kc += 64) {
#pragma unroll
    for (int i = 0; i < 4; ++i) {
      int flat = tid + i * 256;
      int r = flat >> 4;
      int q = flat & 15;
      int gr = row0 + r; if (gr >= n) gr = n - 1;
      float4 xv = *reinterpret_cast<const float4*>(&X[(size_t)gr * K_IN + kc + q * 4]);
      *reinterpret_cast<float4*>(&Xs[r][q * 4]) = xv;
      float4 wv = *reinterpret_cast<const float4*>(&W[(size_t)(kc + r) * N_OUT + q * 4]);
      *reinterpret_cast<float4*>(&Ws[r][q * 4]) = wv;
    }
    __syncthreads();
#pragma unroll
    for (int k = 0; k < 64; ++k) {
      float4 wv = *reinterpret_cast<const float4*>(&Ws[k][tx * 4]);
#pragma unroll
      for (int i = 0; i < 4; ++i) {
        float xv = Xs[ty * 4 + i][k];
        acc[i][0] += xv * wv.x;
        acc[i][1] += xv * wv.y;
        acc[i][2] += xv * wv.z;
        acc[i][3] += xv * wv.w;
      }
    }
    __syncthreads();
  }
#pragma unroll
  for (int i = 0; i < 4; ++i) {
    int gr = row0 + ty * 4 + i;
    if (gr < n) {
      float4 o = make_float4(acc[i][0], acc[i][1], acc[i][2], acc[i][3]);
      *reinterpret_cast<float4*>(&XW[(size_t)gr * N_OUT + tx * 4]) = o;
    }
  }
}

// ---------------- bucket histogram (LDS-privatized) ----------------
__global__ __launch_bounds__(256) void bucket_hist(const int* __restrict__ er,
                                                   int* __restrict__ gh, int E, int NB) {
  __shared__ int h[MAX_NB];
  for (int k = threadIdx.x; k < MAX_NB; k += 256) h[k] = 0;
  __syncthreads();
  for (int i = blockIdx.x * 256 + threadIdx.x; i < E; i += gridDim.x * 256)
    atomicAdd(&h[er[i] >> 7], 1);
  __syncthreads();
  for (int k = threadIdx.x; k < NB; k += 256)
    if (h[k]) atomicAdd(&gh[k], h[k]);
}

// ---------------- exclusive scan of bucket counts (single block) ----------
__global__ __launch_bounds__(256) void scan_small(const int* __restrict__ gh,
    int* __restrict__ boffs, int* __restrict__ gwp, int NB, int E) {
  __shared__ int sc[2][MAX_NB];
  int tid = threadIdx.x;
  for (int k = tid; k < MAX_NB; k += 256) sc[0][k] = (k < NB) ? gh[k] : 0;
  __syncthreads();
  int buf = 0;
  for (int d = 1; d < MAX_NB; d <<= 1) {
    for (int k = tid; k < MAX_NB; k += 256) {
      int v = sc[buf][k];
      if (k >= d) v += sc[buf][k - d];
      sc[buf ^ 1][k] = v;
    }
    buf ^= 1; __syncthreads();
  }
  for (int k = tid; k < NB; k += 256) {
    int ex = (k > 0) ? sc[buf][k - 1] : 0;
    boffs[k] = ex; gwp[k] = ex;
  }
  if (tid == 0) boffs[NB] = E;
}

// ---------------- multisplit: bin edges into bucket-contiguous array -------
// record: int2{ key = (row&127)<<24 | col , valbits }
__global__ __launch_bounds__(256) void multisplit(
    const int* __restrict__ er, const int* __restrict__ ec,
    const float* __restrict__ ev, int* __restrict__ gwp,
    int2* __restrict__ binned, int E) {
  __shared__ int h[MAX_NB];
  __shared__ int sc[2][MAX_NB];
  __shared__ int lsc[MAX_NB];
  __shared__ int base[MAX_NB];
  __shared__ int cursor[MAX_NB];
  __shared__ int2 staged[MS_CHUNK];
  __shared__ unsigned short sbkt[MS_CHUNK];
  const int tid = threadIdx.x;
  const int bb = blockIdx.x * MS_CHUNK;

  for (int k = tid; k < MAX_NB; k += 256) h[k] = 0;
  __syncthreads();

  int rrow[16]; int rcol[16]; float rval[16];
#pragma unroll
  for (int k = 0; k < 16; ++k) {
    int idx = bb + k * 256 + tid;
    if (idx < E) {
      rrow[k] = er[idx]; rcol[k] = ec[idx]; rval[k] = ev[idx];
      atomicAdd(&h[rrow[k] >> 7], 1);
    } else rrow[k] = -1;
  }
  __syncthreads();
  for (int k = tid; k < MAX_NB; k += 256) sc[0][k] = h[k];
  __syncthreads();
  int buf = 0;
  for (int d = 1; d < MAX_NB; d <<= 1) {
    for (int k = tid; k < MAX_NB; k += 256) {
      int v = sc[buf][k];
      if (k >= d) v += sc[buf][k - d];
      sc[buf ^ 1][k] = v;
    }
    buf ^= 1; __syncthreads();
  }
  for (int k = tid; k < MAX_NB; k += 256) {
    int ex = (k > 0) ? sc[buf][k - 1] : 0;
    lsc[k] = ex; cursor[k] = ex;
    int c = h[k];
    base[k] = (c > 0) ? atomicAdd(&gwp[k], c) : 0;
  }
  __syncthreads();
#pragma unroll
  for (int k = 0; k < 16; ++k) {
    if (rrow[k] >= 0) {
      int b = rrow[k] >> 7;
      int pos = atomicAdd(&cursor[b], 1);
      staged[pos] = make_int2(((rrow[k] & 127) << 24) | rcol[k], __float_as_int(rval[k]));
      sbkt[pos] = (unsigned short)b;
    }
  }
  __syncthreads();
  int nv = E - bb; if (nv > MS_CHUNK) nv = MS_CHUNK;
  for (int s = tid; s < nv; s += 256) {
    int b = sbkt[s];
    binned[base[b] + (s - lsc[b])] = staged[s];
  }
}

// ---------------- PRIMARY fused bucket SpMM (sched_barrier pipeline) -------
#define PREP(p) \
  int gi##p = be + 4 * (p) + sub; \
  int2 r##p = (gi##p < s1) ? binned[gi##p] : make_int2(0, 0); \
  float4 g##p = *reinterpret_cast<const float4*>( \
      &xw[((size_t)(r##p.x & 0xFFFFFF) << 6) + (q << 2)]);

#define CONS(p) { \
  int ri = ((unsigned)r##p.x) >> 24; \
  float vv = __int_as_float(r##p.y); \
  int off0 = ((q << 2) + ((ri & 15) << 2)) & 63; \
  float* ap = &acc[(ri << 6) + off0]; \
  atomicAdd(&ap[0], vv * g##p.x); \
  atomicAdd(&ap[1], vv * g##p.y); \
  atomicAdd(&ap[2], vv * g##p.z); \
  atomicAdd(&ap[3], vv * g##p.w); }

__global__ __launch_bounds__(256, 4) void bucket_spmm(
    const int* __restrict__ boffs, const int2* __restrict__ binned,
    const float* __restrict__ xw, const float* __restrict__ bias,
    float* __restrict__ out, int n) {
  __shared__ float acc[RPB * N_OUT];  // 32 KB
  const int tid = threadIdx.x;
  const int lane = tid & 63;
  const int wid = tid >> 6;  // 0..3
  const int sub = lane >> 4;
  const int q = lane & 15;
  const int b = blockIdx.x;
  const int r0 = b * RPB;

  for (int k = tid; k < RPB * N_OUT; k += 256) acc[k] = 0.f;
  __syncthreads();

  const int s0 = boffs[b], s1 = boffs[b + 1];

  for (int be = s0 + wid * 64; be < s1; be += 4 * 64) {
    PREP(0) PREP(1) PREP(2) PREP(3) PREP(4) PREP(5) PREP(6) PREP(7)
    __builtin_amdgcn_sched_barrier(0);
    CONS(0) CONS(1) CONS(2) CONS(3)
    PREP(8) PREP(9) PREP(10) PREP(11)
    __builtin_amdgcn_sched_barrier(0);
    CONS(4) CONS(5) CONS(6) CONS(7)
    PREP(12) PREP(13) PREP(14) PREP(15)
    __builtin_amdgcn_sched_barrier(0);
    CONS(8) CONS(9) CONS(10) CONS(11) CONS(12) CONS(13) CONS(14) CONS(15)
  }
  __syncthreads();

  const float bv = bias[tid & 63];
#pragma unroll
  for (int k = 0; k < 32; ++k) {
    int idx = tid + k * 256;          // 0..8191
    int lr = idx >> 6;                // row in bucket; one row per wave per k
    int f = idx & 63;
    int gr = r0 + lr;
    if (gr < n) {
      float v = acc[(lr << 6) + ((f + ((lr & 15) << 2)) & 63)];
      out[(size_t)gr * N_OUT + f] = fmaxf(v + bv, 0.f);
    }
  }
}

// ---------------- SHADOW: inline-asm forced-MLP variant (A/B probe) --------
// Identical math; all hot-loop VMEM via asm volatile with explicit
// s_waitcnt vmcnt(0) + sched_barrier(0) fences (guide rule #18). 16 record
// loads in flight, then 2x8 gathers in flight — compiler cannot reorder
// volatile asm blocks. Writes to scratch; result unused (A/B timing only).
#define APREP(p) \
  int gi##p = be + 4 * (p) + sub; \
  const int2* bp##p = binned + ((gi##p < s1) ? gi##p : s0); \
  i32x2 r##p; \
  asm volatile("global_load_dwordx2 %0, %1, off" : "=v"(r##p) : "v"(bp##p));

#define AGATH(p) \
  const float* xp##p = xw + (((size_t)(((unsigned)r##p.x) & 0xFFFFFFu)) << 6) + (q << 2); \
  f32x4 g##p; \
  asm volatile("global_load_dwordx4 %0, %1, off" : "=v"(g##p) : "v"(xp##p));

#define ACONS(p) { \
  int ri = ((unsigned)r##p.x) >> 24; \
  float vv = (gi##p < s1) ? __int_as_float(r##p.y) : 0.f; \
  int off0 = ((q << 2) + ((ri & 15) << 2)) & 63; \
  float* ap = &acc[(ri << 6) + off0]; \
  atomicAdd(&ap[0], vv * g##p.x); \
  atomicAdd(&ap[1], vv * g##p.y); \
  atomicAdd(&ap[2], vv * g##p.z); \
  atomicAdd(&ap[3], vv * g##p.w); }

__global__ __launch_bounds__(256, 4) void bucket_spmm_asm(
    const int* __restrict__ boffs, const int2* __restrict__ binned,
    const float* __restrict__ xw, const float* __restrict__ bias,
    float* __restrict__ out, int n) {
  __shared__ float acc[RPB * N_OUT];  // 32 KB
  const int tid = threadIdx.x;
  const int lane = tid & 63;
  const int wid = tid >> 6;
  const int sub = lane >> 4;
  const int q = lane & 15;
  const int b = blockIdx.x;
  const int r0 = b * RPB;

  for (int k = tid; k < RPB * N_OUT; k += 256) acc[k] = 0.f;
  __syncthreads();

  const int s0 = boffs[b], s1 = boffs[b + 1];

  for (int be = s0 + wid * 64; be < s1; be += 4 * 64) {
    APREP(0) APREP(1) APREP(2) APREP(3) APREP(4) APREP(5) APREP(6) APREP(7)
    APREP(8) APREP(9) APREP(10) APREP(11) APREP(12) APREP(13) APREP(14) APREP(15)
    asm volatile("s_waitcnt vmcnt(0)" ::: "memory");
    __builtin_amdgcn_sched_barrier(0);
    AGATH(0) AGATH(1) AGATH(2) AGATH(3) AGATH(4) AGATH(5) AGATH(6) AGATH(7)
    asm volatile("s_waitcnt vmcnt(0)" ::: "memory");
    __builtin_amdgcn_sched_barrier(0);
    ACONS(0) ACONS(1) ACONS(2) ACONS(3) ACONS(4) ACONS(5) ACONS(6) ACONS(7)
    AGATH(8) AGATH(9) AGATH(10) AGATH(11) AGATH(12) AGATH(13) AGATH(14) AGATH(15)
    asm volatile("s_waitcnt vmcnt(0)" ::: "memory");
    __builtin_amdgcn_sched_barrier(0);
    ACONS(8) ACONS(9) ACONS(10) ACONS(11) ACONS(12) ACONS(13) ACONS(14) ACONS(15)
  }
  __syncthreads();

  const float bv = bias[tid & 63];
#pragma unroll
  for (int k = 0; k < 32; ++k) {
    int idx = tid + k * 256;
    int lr = idx >> 6;
    int f = idx & 63;
    int gr = r0 + lr;
    if (gr < n) {
      float v = acc[(lr << 6) + ((f + ((lr & 15) << 2)) & 63)];
      out[(size_t)gr * N_OUT + f] = fmaxf(v + bv, 0.f);
    }
  }
}

// ---------------- atomic fallback (ws too small) ---------------------------
__global__ void spmm_atomic(const int* __restrict__ er, const int* __restrict__ ec,
                            const float* __restrict__ ev, const float* __restrict__ xw,
                            float* __restrict__ out, int E) {
  int wid = (int)((blockIdx.x * blockDim.x + threadIdx.x) >> 6);
  int lane = threadIdx.x & 63;
  if (wid >= E) return;
  int r = er[wid], c = ec[wid];
  float v = ev[wid];
  atomicAdd(&out[(size_t)r * N_OUT + lane], v * xw[(size_t)c * N_OUT + lane]);
}

__global__ void bias_relu(float* __restrict__ out, const float* __restrict__ bias, int total) {
  int i = blockIdx.x * blockDim.x + threadIdx.x;
  if (i < total) out[i] = fmaxf(out[i] + bias[i & (N_OUT - 1)], 0.f);
}

extern "C" void kernel_launch(void* const* d_in, const int* in_sizes, int n_in,
                              void* d_out, int out_size, void* d_ws, size_t ws_size,
                              hipStream_t stream) {
  const float* X    = (const float*)d_in[0];
  const int*   er   = (const int*)d_in[1];
  const int*   ec   = (const int*)d_in[2];
  const float* ev   = (const float*)d_in[3];
  const float* W    = (const float*)d_in[4];
  const float* bias = (const float*)d_in[5];
  const int n = in_sizes[0] / K_IN;
  const int E = in_sizes[1];
  float* out = (float*)d_out;

  const int NB = (n + RPB - 1) / RPB;

  auto rnd = [](size_t b) { return (b + 255) & ~(size_t)255; };
  const size_t sz_xw     = rnd((size_t)n * N_OUT * 4);
  const size_t sz_gh     = rnd((size_t)MAX_NB * 4);
  const size_t sz_boffs  = rnd((size_t)(MAX_NB + 1) * 4);
  const size_t sz_gwp    = rnd((size_t)MAX_NB * 4);
  const size_t sz_binned = rnd((size_t)E * 8);
  const size_t sz_sout   = rnd((size_t)n * N_OUT * 4);
  const size_t need = sz_xw + sz_gh + sz_boffs + sz_gwp + sz_binned;

  char* ws = (char*)d_ws;
  float* xw = (float*)ws; ws += sz_xw;

  gemm_xw<<<(n + 63) / 64, 256, 0, stream>>>(X, W, xw, n);

  if (ws_size >= need && NB <= MAX_NB) {
    int*  gh     = (int*)ws;  ws += sz_gh;
    int*  boffs  = (int*)ws;  ws += sz_boffs;
    int*  gwp    = (int*)ws;  ws += sz_gwp;
    int2* binned = (int2*)ws; ws += sz_binned;

    hipMemsetAsync(gh, 0, (size_t)MAX_NB * 4, stream);
    bucket_hist<<<512, 256, 0, stream>>>(er, gh, E, NB);
    scan_small<<<1, 256, 0, stream>>>(gh, boffs, gwp, NB, E);
    multisplit<<<(E + MS_CHUNK - 1) / MS_CHUNK, 256, 0, stream>>>(er, ec, ev, gwp, binned, E);
    bucket_spmm<<<NB, 256, 0, stream>>>(boffs, binned, xw, bias, out, n);

    // Shadow A/B probe: identical SpMM via inline-asm forced pipeline.
    // Output goes to scratch (discarded); timing read from rocprof.
    if (ws_size >= need + sz_sout) {
      float* sout = (float*)ws;  // next sz_sout bytes of ws
      bucket_spmm_asm<<<NB, 256, 0, stream>>>(boffs, binned, xw, bias, sout, n);
    }
  } else {
    hipMemsetAsync(out, 0, (size_t)n * N_OUT * 4, stream);
    spmm_atomic<<<(E + 3) / 4, 256, 0, stream>>>(er, ec, ev, xw, out, E);
    bias_relu<<<(n * N_OUT + 255) / 256, 256, 0, stream>>>(out, bias, n * N_OUT);
  }
}

// Round 16
// 918.815 us; speedup vs baseline: 1.7508x; 1.7508x over previous
//
#include <hip/hip_runtime.h>

#define K_IN 256
#define N_OUT 64
#define RPB 128          // rows per bucket
#define MAX_NB 1024      // max buckets (supports n <= 131072)
#define MS_CHUNK 4096    // edges per multisplit block

// ---------------- GEMM: XW = X @ W  (fp32 vector, 64x64 tile, 4x4/thread) ---
__global__ __launch_bounds__(256) void gemm_xw(const float* __restrict__ X,
                                               const float* __restrict__ W,
                                               float* __restrict__ XW, int n) {
  __shared__ float Xs[64][68];
  __shared__ float Ws[64][68];
  const int tid = threadIdx.x;
  const int row0 = blockIdx.x * 64;
  const int tx = tid & 15;
  const int ty = tid >> 4;
  float acc[4][4] = {};
  for (int kc = 0; kc < K_IN; kc += 64) {
#pragma unroll
    for (int i = 0; i < 4; ++i) {
      int flat = tid + i * 256;
      int r = flat >> 4;
      int q = flat & 15;
      int gr = row0 + r; if (gr >= n) gr = n - 1;
      float4 xv = *reinterpret_cast<const float4*>(&X[(size_t)gr * K_IN + kc + q * 4]);
      *reinterpret_cast<float4*>(&Xs[r][q * 4]) = xv;
      float4 wv = *reinterpret_cast<const float4*>(&W[(size_t)(kc + r) * N_OUT + q * 4]);
      *reinterpret_cast<float4*>(&Ws[r][q * 4]) = wv;
    }
    __syncthreads();
#pragma unroll
    for (int k = 0; k < 64; ++k) {
      float4 wv = *reinterpret_cast<const float4*>(&Ws[k][tx * 4]);
#pragma unroll
      for (int i = 0; i < 4; ++i) {
        float xv = Xs[ty * 4 + i][k];
        acc[i][0] += xv * wv.x;
        acc[i][1] += xv * wv.y;
        acc[i][2] += xv * wv.z;
        acc[i][3] += xv * wv.w;
      }
    }
    __syncthreads();
  }
#pragma unroll
  for (int i = 0; i < 4; ++i) {
    int gr = row0 + ty * 4 + i;
    if (gr < n) {
      float4 o = make_float4(acc[i][0], acc[i][1], acc[i][2], acc[i][3]);
      *reinterpret_cast<float4*>(&XW[(size_t)gr * N_OUT + tx * 4]) = o;
    }
  }
}

// ---------------- bucket histogram (LDS-privatized) ----------------
__global__ __launch_bounds__(256) void bucket_hist(const int* __restrict__ er,
                                                   int* __restrict__ gh, int E, int NB) {
  __shared__ int h[MAX_NB];
  for (int k = threadIdx.x; k < MAX_NB; k += 256) h[k] = 0;
  __syncthreads();
  for (int i = blockIdx.x * 256 + threadIdx.x; i < E; i += gridDim.x * 256)
    atomicAdd(&h[er[i] >> 7], 1);
  __syncthreads();
  for (int k = threadIdx.x; k < NB; k += 256)
    if (h[k]) atomicAdd(&gh[k], h[k]);
}

// ---------------- exclusive scan of bucket counts (single block) ----------
__global__ __launch_bounds__(256) void scan_small(const int* __restrict__ gh,
    int* __restrict__ boffs, int* __restrict__ gwp, int NB, int E) {
  __shared__ int sc[2][MAX_NB];
  int tid = threadIdx.x;
  for (int k = tid; k < MAX_NB; k += 256) sc[0][k] = (k < NB) ? gh[k] : 0;
  __syncthreads();
  int buf = 0;
  for (int d = 1; d < MAX_NB; d <<= 1) {
    for (int k = tid; k < MAX_NB; k += 256) {
      int v = sc[buf][k];
      if (k >= d) v += sc[buf][k - d];
      sc[buf ^ 1][k] = v;
    }
    buf ^= 1; __syncthreads();
  }
  for (int k = tid; k < NB; k += 256) {
    int ex = (k > 0) ? sc[buf][k - 1] : 0;
    boffs[k] = ex; gwp[k] = ex;
  }
  if (tid == 0) boffs[NB] = E;
}

// ---------------- multisplit: bin edges into bucket-contiguous array -------
// record: int2{ key = (row&127)<<24 | col , valbits }
__global__ __launch_bounds__(256) void multisplit(
    const int* __restrict__ er, const int* __restrict__ ec,
    const float* __restrict__ ev, int* __restrict__ gwp,
    int2* __restrict__ binned, int E) {
  __shared__ int h[MAX_NB];
  __shared__ int sc[2][MAX_NB];
  __shared__ int lsc[MAX_NB];
  __shared__ int base[MAX_NB];
  __shared__ int cursor[MAX_NB];
  __shared__ int2 staged[MS_CHUNK];
  __shared__ unsigned short sbkt[MS_CHUNK];
  const int tid = threadIdx.x;
  const int bb = blockIdx.x * MS_CHUNK;

  for (int k = tid; k < MAX_NB; k += 256) h[k] = 0;
  __syncthreads();

  int rrow[16]; int rcol[16]; float rval[16];
#pragma unroll
  for (int k = 0; k < 16; ++k) {
    int idx = bb + k * 256 + tid;
    if (idx < E) {
      rrow[k] = er[idx]; rcol[k] = ec[idx]; rval[k] = ev[idx];
      atomicAdd(&h[rrow[k] >> 7], 1);
    } else rrow[k] = -1;
  }
  __syncthreads();
  for (int k = tid; k < MAX_NB; k += 256) sc[0][k] = h[k];
  __syncthreads();
  int buf = 0;
  for (int d = 1; d < MAX_NB; d <<= 1) {
    for (int k = tid; k < MAX_NB; k += 256) {
      int v = sc[buf][k];
      if (k >= d) v += sc[buf][k - d];
      sc[buf ^ 1][k] = v;
    }
    buf ^= 1; __syncthreads();
  }
  for (int k = tid; k < MAX_NB; k += 256) {
    int ex = (k > 0) ? sc[buf][k - 1] : 0;
    lsc[k] = ex; cursor[k] = ex;
    int c = h[k];
    base[k] = (c > 0) ? atomicAdd(&gwp[k], c) : 0;
  }
  __syncthreads();
#pragma unroll
  for (int k = 0; k < 16; ++k) {
    if (rrow[k] >= 0) {
      int b = rrow[k] >> 7;
      int pos = atomicAdd(&cursor[b], 1);
      staged[pos] = make_int2(((rrow[k] & 127) << 24) | rcol[k], __float_as_int(rval[k]));
      sbkt[pos] = (unsigned short)b;
    }
  }
  __syncthreads();
  int nv = E - bb; if (nv > MS_CHUNK) nv = MS_CHUNK;
  for (int s = tid; s < nv; s += 256) {
    int b = sbkt[s];
    binned[base[b] + (s - lsc[b])] = staged[s];
  }
}

// ---------------- fused bucket SpMM + bias + ReLU (coalesced gather) -------
// ONE record per wave-iteration, lane = feature:
//   - record index is wave-uniform (readfirstlane) -> key via scalar/broadcast
//   - gather xw[col*64 + lane] = one contiguous 256B load per record
//   - one ds_add_f32 per record: 64 consecutive LDS addrs = 2-way alias, free
// This replaces the divergent 4-record x 16B gather (16 lines/instr) that
// measured ~694us in BOTH compiler-scheduled and asm-forced-pipeline forms.
__global__ __launch_bounds__(256, 4) void bucket_spmm(
    const int* __restrict__ boffs, const int2* __restrict__ binned,
    const float* __restrict__ xw, const float* __restrict__ bias,
    float* __restrict__ out, int n) {
  __shared__ float acc[RPB * N_OUT];  // 32 KB
  const int tid = threadIdx.x;
  const int lane = tid & 63;
  const int wid = tid >> 6;  // 0..3
  const int b = blockIdx.x;
  const int r0 = b * RPB;

  for (int k = tid; k < RPB * N_OUT; k += 256) acc[k] = 0.f;
  __syncthreads();

  const int s0 = boffs[b], s1 = boffs[b + 1];

  for (int be = s0 + wid * 64; be < s1; be += 4 * 64) {
    const int sbe = __builtin_amdgcn_readfirstlane(be);
    int m = s1 - sbe; if (m > 64) m = 64;
#pragma unroll 8
    for (int j = 0; j < m; ++j) {
      int2 rec = binned[sbe + j];                  // wave-uniform address
      int col = rec.x & 0xFFFFFF;
      int ri  = ((unsigned)rec.x) >> 24;
      float v = __int_as_float(rec.y);
      float g = xw[((size_t)col << 6) + lane];     // coalesced 256B
      atomicAdd(&acc[(ri << 6) + lane], v * g);    // ds_add_f32, conflict-free
    }
  }
  __syncthreads();

  const float bv = bias[lane];
#pragma unroll
  for (int k = 0; k < 32; ++k) {
    int idx = tid + k * 256;          // 0..8191
    int lr = idx >> 6;
    int f = idx & 63;
    int gr = r0 + lr;
    if (gr < n)
      out[(size_t)gr * N_OUT + f] = fmaxf(acc[(lr << 6) + f] + bv, 0.f);
  }
}

// ---------------- atomic fallback (ws too small) ---------------------------
__global__ void spmm_atomic(const int* __restrict__ er, const int* __restrict__ ec,
                            const float* __restrict__ ev, const float* __restrict__ xw,
                            float* __restrict__ out, int E) {
  int wid = (int)((blockIdx.x * blockDim.x + threadIdx.x) >> 6);
  int lane = threadIdx.x & 63;
  if (wid >= E) return;
  int r = er[wid], c = ec[wid];
  float v = ev[wid];
  atomicAdd(&out[(size_t)r * N_OUT + lane], v * xw[(size_t)c * N_OUT + lane]);
}

__global__ void bias_relu(float* __restrict__ out, const float* __restrict__ bias, int total) {
  int i = blockIdx.x * blockDim.x + threadIdx.x;
  if (i < total) out[i] = fmaxf(out[i] + bias[i & (N_OUT - 1)], 0.f);
}

extern "C" void kernel_launch(void* const* d_in, const int* in_sizes, int n_in,
                              void* d_out, int out_size, void* d_ws, size_t ws_size,
                              hipStream_t stream) {
  const float* X    = (const float*)d_in[0];
  const int*   er   = (const int*)d_in[1];
  const int*   ec   = (const int*)d_in[2];
  const float* ev   = (const float*)d_in[3];
  const float* W    = (const float*)d_in[4];
  const float* bias = (const float*)d_in[5];
  const int n = in_sizes[0] / K_IN;
  const int E = in_sizes[1];
  float* out = (float*)d_out;

  const int NB = (n + RPB - 1) / RPB;

  auto rnd = [](size_t b) { return (b + 255) & ~(size_t)255; };
  const size_t sz_xw     = rnd((size_t)n * N_OUT * 4);
  const size_t sz_gh     = rnd((size_t)MAX_NB * 4);
  const size_t sz_boffs  = rnd((size_t)(MAX_NB + 1) * 4);
  const size_t sz_gwp    = rnd((size_t)MAX_NB * 4);
  const size_t sz_binned = rnd((size_t)E * 8);
  const size_t need = sz_xw + sz_gh + sz_boffs + sz_gwp + sz_binned;

  char* ws = (char*)d_ws;
  float* xw = (float*)ws; ws += sz_xw;

  gemm_xw<<<(n + 63) / 64, 256, 0, stream>>>(X, W, xw, n);

  if (ws_size >= need && NB <= MAX_NB) {
    int*  gh     = (int*)ws;  ws += sz_gh;
    int*  boffs  = (int*)ws;  ws += sz_boffs;
    int*  gwp    = (int*)ws;  ws += sz_gwp;
    int2* binned = (int2*)ws; ws += sz_binned;

    hipMemsetAsync(gh, 0, (size_t)MAX_NB * 4, stream);
    bucket_hist<<<512, 256, 0, stream>>>(er, gh, E, NB);
    scan_small<<<1, 256, 0, stream>>>(gh, boffs, gwp, NB, E);
    multisplit<<<(E + MS_CHUNK - 1) / MS_CHUNK, 256, 0, stream>>>(er, ec, ev, gwp, binned, E);
    bucket_spmm<<<NB, 256, 0, stream>>>(boffs, binned, xw, bias, out, n);
  } else {
    hipMemsetAsync(out, 0, (size_t)n * N_OUT * 4, stream);
    spmm_atomic<<<(E + 3) / 4, 256, 0, stream>>>(er, ec, ev, xw, out, E);
    bias_relu<<<(n * N_OUT + 255) / 256, 256, 0, stream>>>(out, bias, n * N_OUT);
  }
}